// Round 2
// 810.471 us; speedup vs baseline: 1.1208x; 1.1208x over previous
//
#include <hip/hip_runtime.h>

// out = (fftn(x, axes=all).real + imag) / numel  -- the spectral branch of the
// reference is dead code. 4D FFT over (B=16, C=64, H=256, W=256), separable.
// 3 passes:
//   K1: real 256-pt FFT along W (half-spectrum, kw<=128, padded to WP)
//       -- input staged through LDS as float4 for coalesced dwordx4 loads
//   K2: complex 256-pt FFT along H (in place) -- LDS col stride 273 (odd f2)
//       kills the former 16-way bank conflict
//   K3: fused 64-pt FFT along C + 16-pt FFT along B + (Re+/-Im)/N finalize.
//       16-wide kw tiles, 1024 threads, XOR-swizzled flat LDS = exactly
//       128 KB (proven-working size on gfx950): output stores become
//       64B-aligned 16-float runs (direct AND Hermitian mirror).

#define NB 16
#define NC 64
#define NH 256
#define NW 256
#define WP 132           // padded complex line length along kw (129 used)
#define LSTRIDE (NH*WP)  // stride between consecutive (b*64+c) lines

__device__ __forceinline__ float2 cadd(float2 a, float2 b){ return make_float2(a.x+b.x, a.y+b.y); }
__device__ __forceinline__ float2 csub(float2 a, float2 b){ return make_float2(a.x-b.x, a.y-b.y); }
__device__ __forceinline__ float2 cmul(float2 a, float2 b){ return make_float2(a.x*b.x - a.y*b.y, a.x*b.y + a.y*b.x); }

// e^{-2*pi*i * frac}
__device__ __forceinline__ float2 twd(float frac){
  float sn, cs;
  __sincosf(-6.28318530717958647692f * frac, &sn, &cs);
  return make_float2(cs, sn);
}

// 4-point DFT, natural order in/out
__device__ __forceinline__ void dft4(float2&a,float2&b,float2&c,float2&d){
  float2 t0=cadd(a,c), t1=csub(a,c), t2=cadd(b,d), t3=csub(b,d);
  float2 t3i = make_float2(t3.y, -t3.x);   // -i * t3
  a=cadd(t0,t2); c=csub(t0,t2); b=cadd(t1,t3i); d=csub(t1,t3i);
}

// 8-point FFT, natural order in/out (DIT radix-2 over two DFT4)
__device__ __forceinline__ void fft8(float2 v[8]){
  float2 e0=v[0],e1=v[2],e2=v[4],e3=v[6];
  float2 o0=v[1],o1=v[3],o2=v[5],o3=v[7];
  dft4(e0,e1,e2,e3); dft4(o0,o1,o2,o3);
  const float s=0.70710678118654752440f;
  float2 w1o=make_float2(s*(o1.x+o1.y), s*(o1.y-o1.x));   // e^{-i pi/4} * o1
  float2 w2o=make_float2(o2.y, -o2.x);                    // -i * o2
  float2 w3o=make_float2(s*(o3.y-o3.x), -s*(o3.x+o3.y));  // e^{-i 3pi/4} * o3
  v[0]=cadd(e0,o0); v[4]=csub(e0,o0);
  v[1]=cadd(e1,w1o); v[5]=csub(e1,w1o);
  v[2]=cadd(e2,w2o); v[6]=csub(e2,w2o);
  v[3]=cadd(e3,w3o); v[7]=csub(e3,w3o);
}

// 16-point FFT, natural order in/out (DIT radix-2 over two FFT8)
__device__ __forceinline__ void fft16(float2 v[16]){
  float2 e[8], o[8];
#pragma unroll
  for(int i=0;i<8;i++){ e[i]=v[2*i]; o[i]=v[2*i+1]; }
  fft8(e); fft8(o);
  const float c1=0.92387953251128675613f, s1=0.38268343236508977173f, s=0.70710678118654752440f;
  const float wr[8] = {1.f,  c1,  s,  s1, 0.f, -s1, -s, -c1};
  const float wi[8] = {0.f, -s1, -s, -c1, -1.f, -c1, -s, -s1};
#pragma unroll
  for(int k=0;k<8;k++){
    float2 wo = make_float2(wr[k]*o[k].x - wi[k]*o[k].y, wr[k]*o[k].y + wi[k]*o[k].x);
    v[k]=cadd(e[k],wo); v[k+8]=csub(e[k],wo);
  }
}

// ---------------- K1: real 256-pt FFT along W, store kw<=128 ----------------
// 16 lines/wg; tid&15 = j (position-in-line, n2), tid>>4 = local line (h).
// Input staged into LDS via float4; smem is UNION'd with the transpose buffer
// (extra barrier separates the two uses).
__global__ __launch_bounds__(256) void k1_fftW(const float* __restrict__ x, float2* __restrict__ S){
  __shared__ __align__(16) float smem[16*273*2];     // 34,944 B
  float2* lds2 = (float2*)smem;                      // transpose view, stride 273
  const int t    = threadIdx.x;
  const int j    = t & 15;
  const int line = t >> 4;
  const size_t gbase = (size_t)blockIdx.x * 16;      // first gline of block

  // ---- stage: 16 rows x 256 floats, coalesced float4 ----
  const float4* xv = (const float4*)x;
#pragma unroll
  for(int r=0;r<4;r++){
    int f  = r*256 + t;
    int ln = f >> 6, pos = f & 63;                   // row, float4-within-row
    float4 val = xv[(gbase + ln) * 64 + pos];
    *(float4*)(&smem[ln*264 + pos*4]) = val;         // row stride 264: 2-way max
  }
  __syncthreads();

  float2 v[16];
#pragma unroll
  for(int n1=0;n1<16;n1++) v[n1] = make_float2(smem[line*264 + 16*n1 + j], 0.f);
  __syncthreads();                                   // staging fully read; reuse as lds2

  fft16(v);                                          // inner DFT over n1, index k1
#pragma unroll
  for(int k1=0;k1<16;k1++){
    v[k1] = cmul(v[k1], twd((float)(j*k1) * (1.0f/256.0f)));
    lds2[line*273 + k1*17 + j] = v[k1];              // f2addr%16 = line+k1+j -> uniform
  }
  __syncthreads();
  float2 u[16];
#pragma unroll
  for(int n2=0;n2<16;n2++) u[n2] = lds2[line*273 + j*17 + n2];
  fft16(u);                                          // outer DFT over n2, index k2
  float2* ps = S + (gbase + line) * WP;              // X[j + 16*k2]
#pragma unroll
  for(int k2=0;k2<8;k2++) ps[j + 16*k2] = u[k2];
  if(j==0) ps[128] = u[8];
}

// ---------------- K2: in-place complex 256-pt FFT along H -------------------
// 16 kw columns/wg; tid&15 = kw offset (line id), tid>>4 = j.
// LDS col stride 273 (odd float2): f2addr%16 = kwo+k1+j -> conflict-free
// (old [16][16][17] layout had col stride 272 = 0 mod 16 -> 16-way conflict).
__global__ __launch_bounds__(256) void k2_fftH(float2* __restrict__ S){
  __shared__ float2 lds[16*273];                     // 34,944 B
  const int kwo  = threadIdx.x & 15;
  const int j    = threadIdx.x >> 4;
  const int tile = blockIdx.x % 9;
  const int slice= blockIdx.x / 9;                   // b*64+c
  const int kw   = tile*16 + kwo;
  const bool act = (kw <= 128);
  float2* base = S + (size_t)slice * NH * WP + kw;
  float2 v[16];
#pragma unroll
  for(int n1=0;n1<16;n1++) v[n1] = act ? base[(16*n1 + j) * WP] : make_float2(0.f,0.f);
  fft16(v);
#pragma unroll
  for(int k1=0;k1<16;k1++){
    v[k1] = cmul(v[k1], twd((float)(j*k1) * (1.0f/256.0f)));
    lds[kwo*273 + k1*17 + j] = v[k1];
  }
  __syncthreads();
  float2 u[16];
#pragma unroll
  for(int n2=0;n2<16;n2++) u[n2] = lds[kwo*273 + j*17 + n2];
  fft16(u);
  if(act){
#pragma unroll
    for(int k2=0;k2<16;k2++) base[(j + 16*k2) * WP] = u[k2];
  }
}

// ------- K3: fused C-FFT(64) + B-FFT(16) + finalize, writes d_out -----------
// Workgroup: 1024 threads, fixed h, tile of 16 kw, all (b,c).
// LDS: flat [1024 rows][16 kwo] XOR-swizzled (kwo ^= (row&7)<<1), exactly
// 128 KB -> 1 block/CU, 16 waves (50% ceiling). Swizzle is even -> float4
// pairs stay adjacent; every phase has lanes varying kwo (or part) against a
// per-lane-constant row -> f2addr%16 distinct across 16 lanes -> uniform banks.
// blockIdx.x = tile*256 + h; tiles 0..8 (tile 8 covers kw=128 only).
// 16-wide kw per (kb,kc) row => direct and mirror stores are 64B-aligned
// 16-float contiguous runs -> no partial-sector write amplification.
#define AIX(row,kwo) (((row)<<4) + ((kwo) ^ (((row)&7)<<1)))
__global__ __launch_bounds__(1024) void k3_fused(const float2* __restrict__ S, float* __restrict__ out){
  __shared__ __align__(16) float2 A[1024*16];        // 131,072 B
  const int t    = threadIdx.x;
  const int h    = blockIdx.x & 255;
  const int tile = blockIdx.x >> 8;                  // 0..8
  const int kw0  = tile * 16;
  const float2* Sbase = S + (size_t)h * WP + kw0;

  // ---- load: 1024 lines x 16 complex (= 8 float4 per line, 128B/line) ----
#pragma unroll
  for(int r=0;r<8;r++){
    int f    = t + 1024*r;                           // 0..8191
    int line = f >> 3;                               // bc = b*64+c
    int part = f & 7;                                // which float4 (2 complex)
    float4 val;
    if(kw0 + part*2 + 1 < WP){
      val = *(const float4*)(Sbase + (size_t)line * LSTRIDE + part*2);
    } else {
      val = make_float4(0.f,0.f,0.f,0.f);            // tile 8 tail, never used
    }
    *(float4*)(&A[AIX(line, part*2)]) = val;         // swizzle even -> pair adjacent
  }
  __syncthreads();

  // ---- stage C1: 8-pt FFT over n1 (c = 8*n1 + n2), twiddle ----
  // items (b, n2, kwo): element sets disjoint per item -> in-place safe.
  // row&7 = n2 for all touched rows -> swizzle const per item.
#pragma unroll
  for(int q=0;q<2;q++){
    int item = t + 1024*q;
    int kwo = item & 15, n2 = (item>>4) & 7, b = item >> 7;
    float2 v[8];
#pragma unroll
    for(int n1=0;n1<8;n1++) v[n1] = A[AIX(b*64 + 8*n1 + n2, kwo)];
    fft8(v);                                         // -> k1
#pragma unroll
    for(int k1=0;k1<8;k1++) A[AIX(b*64 + 8*k1 + n2, kwo)] = cmul(v[k1], twd((float)(n2*k1) * (1.0f/64.0f)));
  }
  __syncthreads();

  // ---- stage C2: 8-pt FFT over n2 for fixed k1; c-freq kc = k1 + 8*k2 ----
  // cross-item write hazard -> read all, sync, write all.
  {
    float2 u[2][8];
#pragma unroll
    for(int q=0;q<2;q++){
      int item = t + 1024*q;
      int kwo = item & 15, k1 = (item>>4) & 7, b = item >> 7;
#pragma unroll
      for(int n2=0;n2<8;n2++) u[q][n2] = A[AIX(b*64 + 8*k1 + n2, kwo)];
      fft8(u[q]);                                    // -> k2
    }
    __syncthreads();
#pragma unroll
    for(int q=0;q<2;q++){
      int item = t + 1024*q;
      int kwo = item & 15, k1 = (item>>4) & 7, b = item >> 7;
#pragma unroll
      for(int k2=0;k2<8;k2++) A[AIX(b*64 + (k1 + 8*k2), kwo)] = u[q][k2];
    }
  }
  __syncthreads();

  // ---- stage B: 16-pt FFT over b, then finalize writes ----
  const float inv = 1.0f / 67108864.0f;
  const int h2 = (NH - h) & 255;
  {
    int kwo = t & 15, kc = t >> 4;                   // kc 0..63, 1 item/thread
    float2 v[16];
#pragma unroll
    for(int b=0;b<16;b++) v[b] = A[AIX(b*64 + kc, kwo)];
    fft16(v);                                        // -> kb
    const int kw = kw0 + kwo;
    if(kw <= 128){
      const int kc2 = (NC - kc) & 63;
#pragma unroll
      for(int kb=0;kb<16;kb++){
        float2 z = v[kb];
        out[(((size_t)kb*NC + kc)*NH + h)*NW + kw] = (z.x + z.y) * inv;
        if(kw >= 1 && kw <= 127){
          const int kb2 = (16 - kb) & 15;
          out[(((size_t)kb2*NC + kc2)*NH + h2)*NW + (NW - kw)] = (z.x - z.y) * inv;
        }
      }
    }
  }
}

extern "C" void kernel_launch(void* const* d_in, const int* in_sizes, int n_in,
                              void* d_out, int out_size, void* d_ws, size_t ws_size,
                              hipStream_t stream) {
  const float* x = (const float*)d_in[0];   // (16,64,256,256) fp32
  // d_in[1], d_in[2] (weights) and d_in[3] (error_estimate) are dead code.
  float* out = (float*)d_out;               // (16,64,256,256) fp32
  float2* S  = (float2*)d_ws;               // 16*64*256*132*8 = ~264 MiB

  k1_fftW<<<NB*NC*NH/16, 256,  0, stream>>>(x, S);   // 16384 blocks
  k2_fftH<<<NB*NC*9,     256,  0, stream>>>(S);      // 9216 blocks
  k3_fused<<<9*256,      1024, 0, stream>>>(S, out); // 2304 blocks
}